// Round 2
// baseline (41.051 us; speedup 1.0000x reference)
//
#include <hip/hip_runtime.h>

#define NQ 11

// Two waves per sample. Amplitude index i (11 bits, wire w <-> bit (10-w)):
//   i = (b<<10) | (r<<6) | lane
//   wire 0      -> wave bit b            (LDS-exchange butterfly, 1/layer)
//   wires 1..4  -> r bits 3..0           (in-register butterflies)
//   wires 5..10 -> lane bits 5..0        (__shfl_xor butterflies)
// All CZ gates are folded into the coefficients of the following RY
// (signs factor out of a butterfly when both pre-signs are equal; only the
// relative sign remains, which is a compile-time or per-lane constant).
// The final CZ(10,0) of the last layer is dropped: probs = amp^2.

// RY on r-bit RB, folding the preceding CZ whose sign is -1 iff (r0 & PSB).
#define RY_REG_F(RB, PSB, C, S)                                              \
    _Pragma("unroll")                                                        \
    for (int g = 0; g < 8; ++g) {                                            \
        const int r0 = ((g >> (RB)) << ((RB) + 1)) | (g & ((1 << (RB)) - 1));\
        const int r1 = r0 | (1 << (RB));                                     \
        const float a_ = v[r0], b_ = v[r1];                                  \
        if (r0 & (PSB)) {                                                    \
            v[r0] = (C) * a_ + (S) * b_;                                     \
            v[r1] = (S) * a_ - (C) * b_;                                     \
        } else {                                                             \
            v[r0] = (C) * a_ - (S) * b_;                                     \
            v[r1] = (S) * a_ + (C) * b_;                                     \
        }                                                                    \
    }

// Lane butterfly with uniform folded coefficients (own CM, cross SM)
#define RY_LANE_F(MASK, CM, SM)                                              \
    _Pragma("unroll")                                                        \
    for (int r = 0; r < 16; ++r) {                                           \
        const float pa_ = __shfl_xor(v[r], (MASK));                          \
        v[r] = (CM) * v[r] + (SM) * pa_;                                     \
    }

__global__ __launch_bounds__(256) void qru_kernel(
    const float* __restrict__ x,   // [2048, 16]
    const float* __restrict__ w,   // [11]
    float* __restrict__ out)       // [2048, 11]
{
    const int tid  = threadIdx.x;
    const int lane = tid & 63;
    const int wid  = tid >> 6;      // 0..3
    const int sloc = wid >> 1;      // sample within block
    const int b    = wid & 1;       // wave bit = wire 0
    const int n    = blockIdx.x * 2 + sloc;

    __shared__ float buf[2][2][2][16][64];  // [dbuf][sloc][b][r][lane], 32 KB
    __shared__ float qbuf[4][12];

    // ---- half-angle sin/cos ----
    float ci[NQ], si[NQ];
#pragma unroll
    for (int q = 0; q < NQ; ++q) {
        const float h = x[n * 16 + q] * 0.5f;
        si[q] = __sinf(h); ci[q] = __cosf(h);
    }
    float cw[NQ], sw[NQ];
#pragma unroll
    for (int q = 0; q < NQ; ++q) {
        const float h = w[q] * 0.5f;
        sw[q] = __sinf(h); cw[q] = __cosf(h);
    }

    // ---- initial product state ----
    const float laneF =
        ((lane & 32) ? si[5]  : ci[5])  *
        ((lane & 16) ? si[6]  : ci[6])  *
        ((lane & 8)  ? si[7]  : ci[7])  *
        ((lane & 4)  ? si[8]  : ci[8])  *
        ((lane & 2)  ? si[9]  : ci[9])  *
        ((lane & 1)  ? si[10] : ci[10]);
    const float wf = (b ? si[0] : ci[0]) * laneF;

    float v[16];
#pragma unroll
    for (int r = 0; r < 16; ++r) {
        v[r] = wf * ((r & 8) ? si[1] : ci[1])
                  * ((r & 4) ? si[2] : ci[2])
                  * ((r & 2) ? si[3] : ci[3])
                  * ((r & 1) ? si[4] : ci[4]);
    }

    // ---- folded coefficient constants ----
    const int l0 = lane & 1;
    // RY0 layer 0 (no incoming CZ): own cw0, cross:
    const float S0p = b ? sw[0] : -sw[0];
    // RY0 layers>=1 (incoming CZ(10,0): sigma=-1 iff l0&&b):
    const float C0m = (l0 && b) ? -cw[0] : cw[0];
    const float S0m = b ? sw[0] : (l0 ? sw[0] : -sw[0]);
    // RY1 (CZ(0,1): sigma1=-1 iff b)
    const float S1n = b ? sw[1] : -sw[1];   // coeff on partner in n0
    const float C1n = b ? -cw[1] : cw[1];   // coeff on partner in n1
    // RY5 (CZ(4,5): r bit0 & lane bit5)
    const float SS5 = (lane & 32) ? sw[5] : -sw[5];   // even-r cross
    const float C5m = (lane & 32) ? -cw[5] : cw[5];   // odd-r own (cross = +sw5)
    // lane-lane folds: own = (la&&lb)? -C : C ; cross = (la||lb)? +S : -S
    const float C6m  = ((lane & 48) == 48) ? -cw[6]  : cw[6];
    const float S6m  = (lane & 48) ? sw[6]  : -sw[6];
    const float C7m  = ((lane & 24) == 24) ? -cw[7]  : cw[7];
    const float S7m  = (lane & 24) ? sw[7]  : -sw[7];
    const float C8m  = ((lane & 12) == 12) ? -cw[8]  : cw[8];
    const float S8m  = (lane & 12) ? sw[8]  : -sw[8];
    const float C9m  = ((lane & 6)  == 6)  ? -cw[9]  : cw[9];
    const float S9m  = (lane & 6)  ? sw[9]  : -sw[9];
    const float C10m = ((lane & 3)  == 3)  ? -cw[10] : cw[10];
    const float S10m = (lane & 3)  ? sw[10] : -sw[10];

    // ---- 6 layers ----
#pragma unroll 1
    for (int l = 0; l < 6; ++l) {
        // RY0 on the wave bit: LDS exchange (double-buffered, 1 barrier)
        float* wp = &buf[l & 1][sloc][b][0][0];
#pragma unroll
        for (int r = 0; r < 16; ++r) wp[r * 64 + lane] = v[r];
        __syncthreads();
        const float* rp = &buf[l & 1][sloc][b ^ 1][0][0];
        const float cc = (l == 0) ? cw[0] : C0m;
        const float ss = (l == 0) ? S0p  : S0m;
#pragma unroll
        for (int r = 0; r < 16; ++r) {
            const float pa_ = rp[r * 64 + lane];
            v[r] = cc * v[r] + ss * pa_;
        }

        // RY1 (r bit 3), fold CZ(0,1) via wave bit
#pragma unroll
        for (int g = 0; g < 8; ++g) {
            const float a_ = v[g], b_ = v[g | 8];
            v[g]     = cw[1] * a_ + S1n * b_;
            v[g | 8] = sw[1] * a_ + C1n * b_;
        }
        RY_REG_F(2, 8, cw[2], sw[2])    // RY2, fold CZ(1,2) (r bit3)
        RY_REG_F(1, 4, cw[3], sw[3])    // RY3, fold CZ(2,3) (r bit2)
        RY_REG_F(0, 2, cw[4], sw[4])    // RY4, fold CZ(3,4) (r bit1)

        // RY5 (lane mask 32), fold CZ(4,5) (r bit0 & lane bit5)
#pragma unroll
        for (int r = 0; r < 16; ++r) {
            const float pa_ = __shfl_xor(v[r], 32);
            v[r] = (r & 1) ? (C5m * v[r] + sw[5] * pa_)
                           : (cw[5] * v[r] + SS5 * pa_);
        }
        RY_LANE_F(16, C6m,  S6m)        // RY6,  fold CZ(5,6)
        RY_LANE_F(8,  C7m,  S7m)        // RY7,  fold CZ(6,7)
        RY_LANE_F(4,  C8m,  S8m)        // RY8,  fold CZ(7,8)
        RY_LANE_F(2,  C9m,  S9m)        // RY9,  fold CZ(8,9)
        RY_LANE_F(1,  C10m, S10m)       // RY10, fold CZ(9,10)
        // CZ(10,0) folds into next layer's RY0 (C0m/S0m); after the last
        // layer it is a pure sign -> irrelevant to probabilities.
    }

    // ---- measurement ----
    float p[16];
#pragma unroll
    for (int r = 0; r < 16; ++r) p[r] = v[r] * v[r];

    float tot = 0.f;
#pragma unroll
    for (int r = 0; r < 16; ++r) tot += p[r];

    float S3 = 0.f, S2 = 0.f, S1 = 0.f, S0 = 0.f;
#pragma unroll
    for (int r = 0; r < 16; ++r) {
        if (r & 8) S3 += p[r];
        if (r & 4) S2 += p[r];
        if (r & 2) S1 += p[r];
        if (r & 1) S0 += p[r];
    }

    float q[NQ];
    q[0] = b ? -tot : tot;              // wire 0 (wave bit)
    q[1] = tot - 2.f * S3;              // wires 1..4 (r bits 3..0)
    q[2] = tot - 2.f * S2;
    q[3] = tot - 2.f * S1;
    q[4] = tot - 2.f * S0;
    q[5]  = (lane & 32) ? -tot : tot;   // wires 5..10 (lane bits 5..0)
    q[6]  = (lane & 16) ? -tot : tot;
    q[7]  = (lane & 8)  ? -tot : tot;
    q[8]  = (lane & 4)  ? -tot : tot;
    q[9]  = (lane & 2)  ? -tot : tot;
    q[10] = (lane & 1)  ? -tot : tot;

#pragma unroll
    for (int wq = 0; wq < NQ; ++wq) {
        float a = q[wq];
        a += __shfl_xor(a, 32);
        a += __shfl_xor(a, 16);
        a += __shfl_xor(a, 8);
        a += __shfl_xor(a, 4);
        a += __shfl_xor(a, 2);
        a += __shfl_xor(a, 1);
        q[wq] = a;
    }

    if (lane == 0) {
#pragma unroll
        for (int wq = 0; wq < NQ; ++wq) qbuf[wid][wq] = q[wq];
    }
    __syncthreads();
    if (b == 0 && lane < NQ) {
        out[n * NQ + lane] = qbuf[wid][lane] + qbuf[wid + 1][lane];
    }
}

extern "C" void kernel_launch(void* const* d_in, const int* in_sizes, int n_in,
                              void* d_out, int out_size, void* d_ws, size_t ws_size,
                              hipStream_t stream) {
    const float* x = (const float*)d_in[0];   // [8,256,16] f32
    const float* w = (const float*)d_in[1];   // [11] f32
    float* out = (float*)d_out;               // [8,256,11] f32

    // 2048 samples, 2 waves each, 4 waves (2 samples) per block -> 1024 blocks
    qru_kernel<<<1024, 256, 0, stream>>>(x, w, out);
}

// Round 3
// 36.527 us; speedup vs baseline: 1.1239x; 1.1239x over previous
//
#include <hip/hip_runtime.h>

#define NQ 11

// One wave per sample; 2048-amplitude real statevector in 32 VGPRs/lane.
// Amplitude index i = (r<<6) | lane  (wire w <-> bit (10-w) of i):
//   wires 0..4  -> r bits 4..0   (in-register butterflies)
//   wires 5..10 -> lane bits 5..0 (__shfl_xor butterflies)
// Every CZ is folded into the NEXT RY's coefficients:
//   pair (i0: bit_t=0, i1: bit_t=1); sigma1 = -1 iff the CZ's other bit set:
//     new0 = C*u0 - S*sigma1*u1 ;  new1 = S*u0 + C*sigma1*u1
// The trailing CZ(10,0) of the last layer is a pure sign -> dropped (probs).

// RY on r-bit RB, preceding CZ's other bit = PSB (a different r bit).
#define RY_REG_F(RB, PSB, C, S)                                              \
    _Pragma("unroll")                                                        \
    for (int g = 0; g < 16; ++g) {                                           \
        const int r0 = ((g >> (RB)) << ((RB) + 1)) | (g & ((1 << (RB)) - 1));\
        const int r1 = r0 | (1 << (RB));                                     \
        const float a_ = v[r0], b_ = v[r1];                                  \
        if (r0 & (PSB)) {  /* sigma1 = -1 */                                 \
            v[r0] = (C) * a_ + (S) * b_;                                     \
            v[r1] = (S) * a_ - (C) * b_;                                     \
        } else {                                                             \
            v[r0] = (C) * a_ - (S) * b_;                                     \
            v[r1] = (S) * a_ + (C) * b_;                                     \
        }                                                                    \
    }

// Lane butterfly, folded lane-lane CZ: own CM, cross SM (per-lane constants)
#define RY_LANE_F(MASK, CM, SM)                                              \
    _Pragma("unroll")                                                        \
    for (int r = 0; r < 32; ++r) {                                           \
        const float pa_ = __shfl_xor(v[r], (MASK));                          \
        v[r] = (CM) * v[r] + (SM) * pa_;                                     \
    }

__global__ __launch_bounds__(256, 2) void qru_kernel(
    const float* __restrict__ x,   // [2048, 16]
    const float* __restrict__ w,   // [11]
    float* __restrict__ out)       // [2048, 11]
{
    const int lane = threadIdx.x & 63;
    const int n    = blockIdx.x * 4 + (threadIdx.x >> 6);

    // ---- vectorized input load + half-angle sin/cos ----
    const float4 xa = *(const float4*)(x + n * 16);
    const float4 xb = *(const float4*)(x + n * 16 + 4);
    const float4 xc = *(const float4*)(x + n * 16 + 8);
    const float xv[NQ] = {xa.x, xa.y, xa.z, xa.w, xb.x, xb.y, xb.z, xb.w,
                          xc.x, xc.y, xc.z};
    float ci[NQ], si[NQ];
#pragma unroll
    for (int q = 0; q < NQ; ++q) {
        const float h = xv[q] * 0.5f;
        si[q] = __sinf(h); ci[q] = __cosf(h);
    }
    float cw[NQ], sw[NQ];
#pragma unroll
    for (int q = 0; q < NQ; ++q) {
        const float h = w[q] * 0.5f;
        sw[q] = __sinf(h); cw[q] = __cosf(h);
    }

    // ---- initial product state ----
    const float laneF =
        ((lane & 32) ? si[5]  : ci[5])  *
        ((lane & 16) ? si[6]  : ci[6])  *
        ((lane & 8)  ? si[7]  : ci[7])  *
        ((lane & 4)  ? si[8]  : ci[8])  *
        ((lane & 2)  ? si[9]  : ci[9])  *
        ((lane & 1)  ? si[10] : ci[10]);

    float v[32];
#pragma unroll
    for (int r = 0; r < 32; ++r) {
        v[r] = laneF * ((r & 16) ? si[0] : ci[0])
                     * ((r & 8)  ? si[1] : ci[1])
                     * ((r & 4)  ? si[2] : ci[2])
                     * ((r & 2)  ? si[3] : ci[3])
                     * ((r & 1)  ? si[4] : ci[4]);
    }

    // ---- folded per-lane coefficient constants ----
    // RY0 (r bit4), incoming CZ(10,0): sigma1 = -1 iff lane bit0
    const float X0m = (lane & 1) ?  sw[0] : -sw[0];  // u1-coeff in new0
    const float Y0m = (lane & 1) ? -cw[0] :  cw[0];  // u1-coeff in new1
    // RY5 (lane bit5), incoming CZ(4,5): sigma depends on r bit0 & lane bit5
    const float C5m = (lane & 32) ? -cw[5] : cw[5];  // odd-r own
    const float SS5 = (lane & 32) ?  sw[5] : -sw[5]; // even-r cross
    // lane-lane folds: own = (both bits)? -C : C ; cross = (either)? +S : -S
    const float C6m  = ((lane & 48) == 48) ? -cw[6]  : cw[6];
    const float S6m  = (lane & 48) ? sw[6]  : -sw[6];
    const float C7m  = ((lane & 24) == 24) ? -cw[7]  : cw[7];
    const float S7m  = (lane & 24) ? sw[7]  : -sw[7];
    const float C8m  = ((lane & 12) == 12) ? -cw[8]  : cw[8];
    const float S8m  = (lane & 12) ? sw[8]  : -sw[8];
    const float C9m  = ((lane & 6)  == 6)  ? -cw[9]  : cw[9];
    const float S9m  = (lane & 6)  ? sw[9]  : -sw[9];
    const float C10m = ((lane & 3)  == 3)  ? -cw[10] : cw[10];
    const float S10m = (lane & 3)  ? sw[10] : -sw[10];

    auto layer = [&](float X0, float Y0) {
        // RY0 on r bit 4 (incoming CZ folded into X0/Y0)
#pragma unroll
        for (int g = 0; g < 16; ++g) {
            const float a_ = v[g], b_ = v[g | 16];
            v[g]      = cw[0] * a_ + X0 * b_;
            v[g | 16] = sw[0] * a_ + Y0 * b_;
        }
        RY_REG_F(3, 16, cw[1], sw[1])   // RY1, fold CZ(0,1) (r bit4)
        RY_REG_F(2, 8,  cw[2], sw[2])   // RY2, fold CZ(1,2) (r bit3)
        RY_REG_F(1, 4,  cw[3], sw[3])   // RY3, fold CZ(2,3) (r bit2)
        RY_REG_F(0, 2,  cw[4], sw[4])   // RY4, fold CZ(3,4) (r bit1)

        // RY5 (lane bit5), fold CZ(4,5) (r bit0 & lane bit5)
#pragma unroll
        for (int r = 0; r < 32; ++r) {
            const float pa_ = __shfl_xor(v[r], 32);
            v[r] = (r & 1) ? (C5m  * v[r] + sw[5] * pa_)
                           : (cw[5] * v[r] + SS5  * pa_);
        }
        RY_LANE_F(16, C6m,  S6m)        // RY6,  fold CZ(5,6)
        RY_LANE_F(8,  C7m,  S7m)        // RY7,  fold CZ(6,7)
        RY_LANE_F(4,  C8m,  S8m)        // RY8,  fold CZ(7,8)
        RY_LANE_F(2,  C9m,  S9m)        // RY9,  fold CZ(8,9)
        RY_LANE_F(1,  C10m, S10m)       // RY10, fold CZ(9,10)
        // CZ(10,0) -> folded into next layer's RY0 (X0m/Y0m); after the
        // last layer it is a pure sign, irrelevant to probabilities.
    };

    // layer 0: RY0 has no incoming CZ
    layer(-sw[0], cw[0]);
#pragma unroll 1
    for (int l = 1; l < 6; ++l) layer(X0m, Y0m);

    // ---- measurement: out[w] = sum_i amp_i^2 * (1 - 2*bit_w(i)) ----
    float p[32];
#pragma unroll
    for (int r = 0; r < 32; ++r) p[r] = v[r] * v[r];

    float tot = 0.f;
#pragma unroll
    for (int r = 0; r < 32; ++r) tot += p[r];

    float S4 = 0.f, S3 = 0.f, S2 = 0.f, S1 = 0.f, S0 = 0.f;
#pragma unroll
    for (int r = 0; r < 32; ++r) {
        if (r & 16) S4 += p[r];
        if (r & 8)  S3 += p[r];
        if (r & 4)  S2 += p[r];
        if (r & 2)  S1 += p[r];
        if (r & 1)  S0 += p[r];
    }

    float q[NQ];
    q[0] = tot - 2.f * S4;              // wires 0..4 (r bits 4..0)
    q[1] = tot - 2.f * S3;
    q[2] = tot - 2.f * S2;
    q[3] = tot - 2.f * S1;
    q[4] = tot - 2.f * S0;
    q[5]  = (lane & 32) ? -tot : tot;   // wires 5..10 (lane bits 5..0)
    q[6]  = (lane & 16) ? -tot : tot;
    q[7]  = (lane & 8)  ? -tot : tot;
    q[8]  = (lane & 4)  ? -tot : tot;
    q[9]  = (lane & 2)  ? -tot : tot;
    q[10] = (lane & 1)  ? -tot : tot;

#pragma unroll
    for (int wq = 0; wq < NQ; ++wq) {
        float a = q[wq];
        a += __shfl_xor(a, 32);
        a += __shfl_xor(a, 16);
        a += __shfl_xor(a, 8);
        a += __shfl_xor(a, 4);
        a += __shfl_xor(a, 2);
        a += __shfl_xor(a, 1);
        q[wq] = a;
    }

    if (lane == 0) {
#pragma unroll
        for (int wq = 0; wq < NQ; ++wq) out[n * 11 + wq] = q[wq];
    }
}

extern "C" void kernel_launch(void* const* d_in, const int* in_sizes, int n_in,
                              void* d_out, int out_size, void* d_ws, size_t ws_size,
                              hipStream_t stream) {
    const float* x = (const float*)d_in[0];   // [8,256,16] f32
    const float* w = (const float*)d_in[1];   // [11] f32
    float* out = (float*)d_out;               // [8,256,11] f32

    // 2048 samples, 1 wave each, 4 waves per block -> 512 blocks
    qru_kernel<<<512, 256, 0, stream>>>(x, w, out);
}

// Round 5
// 28.224 us; speedup vs baseline: 1.4545x; 1.2942x over previous
//
#include <hip/hip_runtime.h>

#define NQ 11

// One wave per sample; 2048-amplitude real statevector in 32 VGPRs/lane.
// Amplitude index i = (r<<6) | lane  (wire w <-> bit (10-w) of i):
//   wires 0..4  -> r bits 4..0   (in-register butterflies)
//   wires 5..10 -> lane bits 5..0 (cross-lane butterflies)
// Every CZ is folded into the NEXT RY's coefficients (verified rounds 2-3).
// The trailing CZ(10,0) of the last layer is a pure sign -> dropped (probs).
//
// Cross-lane mechanism per mask (this round):
//   mask 32, 16 -> __shfl_xor (ds_bpermute, DS pipe)  [known-correct]
//   mask 8      -> DPP row_ror:8   (rotation by half-row == xor-8, VALU)
//   mask 4      -> DPP row_half_mirror (xor-7) + quad_perm xor-3 == xor-4
//   mask 2      -> DPP quad_perm [2,3,0,1] (xor-2)
//   mask 1      -> DPP quad_perm [1,0,3,2] (xor-1)
// All DPP controls are involutive xor-permutations: no direction ambiguity.

template <int CTRL>
__device__ __forceinline__ float dpp_mov(float x) {
    const int xi = __builtin_bit_cast(int, x);
    return __builtin_bit_cast(float,
        __builtin_amdgcn_update_dpp(xi, xi, CTRL, 0xf, 0xf, false));
}
#define DPP_XOR1 0xB1   // quad_perm [1,0,3,2]
#define DPP_XOR2 0x4E   // quad_perm [2,3,0,1]
#define DPP_XOR3 0x1B   // quad_perm [3,2,1,0]
#define DPP_XOR7 0x141  // row_half_mirror
#define DPP_XOR8 0x128  // row_ror:8 (xor-8 within 16-lane row)

// RY on r-bit RB, preceding CZ's other bit = PSB (another r bit); all VALU.
#define RY_REG_F(RB, PSB, C, S)                                              \
    _Pragma("unroll")                                                        \
    for (int g = 0; g < 16; ++g) {                                           \
        const int r0 = ((g >> (RB)) << ((RB) + 1)) | (g & ((1 << (RB)) - 1));\
        const int r1 = r0 | (1 << (RB));                                     \
        const float a_ = v[r0], b_ = v[r1];                                  \
        if (r0 & (PSB)) {  /* sigma1 = -1 */                                 \
            v[r0] = (C) * a_ + (S) * b_;                                     \
            v[r1] = (S) * a_ - (C) * b_;                                     \
        } else {                                                             \
            v[r0] = (C) * a_ - (S) * b_;                                     \
            v[r1] = (S) * a_ + (C) * b_;                                     \
        }                                                                    \
    }

// Lane butterfly with partner fetched by PGET (folded CZ in CM/SM constants)
#define RY_LANE_G(PGET, CM, SM)                                              \
    _Pragma("unroll")                                                        \
    for (int r = 0; r < 32; ++r) {                                           \
        const float pa_ = PGET(v[r]);                                        \
        v[r] = (CM) * v[r] + (SM) * pa_;                                     \
    }

__global__ __launch_bounds__(256, 2) void qru_kernel(
    const float* __restrict__ x,   // [2048, 16]
    const float* __restrict__ w,   // [11]
    float* __restrict__ out)       // [2048, 11]
{
    const int lane = threadIdx.x & 63;
    const int n    = blockIdx.x * 4 + (threadIdx.x >> 6);

    // ---- input angles (vectorized) + half-angle sin/cos ----
    const float4 xa = *(const float4*)(x + n * 16);
    const float4 xb = *(const float4*)(x + n * 16 + 4);
    const float4 xc = *(const float4*)(x + n * 16 + 8);
    const float xv[NQ] = {xa.x, xa.y, xa.z, xa.w, xb.x, xb.y, xb.z, xb.w,
                          xc.x, xc.y, xc.z};
    float ci[NQ], si[NQ];
#pragma unroll
    for (int q = 0; q < NQ; ++q) {
        const float h = xv[q] * 0.5f;
        si[q] = __sinf(h); ci[q] = __cosf(h);
    }
    float cw[NQ], sw[NQ];
#pragma unroll
    for (int q = 0; q < NQ; ++q) {
        const float h = w[q] * 0.5f;
        sw[q] = __sinf(h); cw[q] = __cosf(h);
    }

    // ---- initial product state ----
    const float laneF =
        ((lane & 32) ? si[5]  : ci[5])  *
        ((lane & 16) ? si[6]  : ci[6])  *
        ((lane & 8)  ? si[7]  : ci[7])  *
        ((lane & 4)  ? si[8]  : ci[8])  *
        ((lane & 2)  ? si[9]  : ci[9])  *
        ((lane & 1)  ? si[10] : ci[10]);

    float v[32];
#pragma unroll
    for (int r = 0; r < 32; ++r) {
        v[r] = laneF * ((r & 16) ? si[0] : ci[0])
                     * ((r & 8)  ? si[1] : ci[1])
                     * ((r & 4)  ? si[2] : ci[2])
                     * ((r & 2)  ? si[3] : ci[3])
                     * ((r & 1)  ? si[4] : ci[4]);
    }

    // ---- folded per-lane coefficient constants (verified round 3) ----
    // RY0 (r bit4), incoming CZ(10,0): sigma1 = -1 iff lane bit0
    const float X0m = (lane & 1) ?  sw[0] : -sw[0];
    const float Y0m = (lane & 1) ? -cw[0] :  cw[0];
    // RY5 (lane bit5), incoming CZ(4,5) (r bit0 & lane bit5):
    const float SS5 = (lane & 32) ?  sw[5] : -sw[5];  // even-r cross
    const float C5m = (lane & 32) ? -cw[5] :  cw[5];  // odd-r own
    // lane-lane folds: own = (both bits)? -C : C ; cross = (either)? +S : -S
    const float C6m  = ((lane & 48) == 48) ? -cw[6]  : cw[6];
    const float S6m  = (lane & 48) ? sw[6]  : -sw[6];
    const float C7m  = ((lane & 24) == 24) ? -cw[7]  : cw[7];
    const float S7m  = (lane & 24) ? sw[7]  : -sw[7];
    const float C8m  = ((lane & 12) == 12) ? -cw[8]  : cw[8];
    const float S8m  = (lane & 12) ? sw[8]  : -sw[8];
    const float C9m  = ((lane & 6)  == 6)  ? -cw[9]  : cw[9];
    const float S9m  = (lane & 6)  ? sw[9]  : -sw[9];
    const float C10m = ((lane & 3)  == 3)  ? -cw[10] : cw[10];
    const float S10m = (lane & 3)  ? sw[10] : -sw[10];

    auto shfl32 = [](float t) { return __shfl_xor(t, 32); };
    auto shfl16 = [](float t) { return __shfl_xor(t, 16); };
    auto dppx8  = [](float t) { return dpp_mov<DPP_XOR8>(t); };
    auto dppx4  = [](float t) { return dpp_mov<DPP_XOR3>(dpp_mov<DPP_XOR7>(t)); };
    auto dppx2  = [](float t) { return dpp_mov<DPP_XOR2>(t); };
    auto dppx1  = [](float t) { return dpp_mov<DPP_XOR1>(t); };

    auto layer = [&](float X0, float Y0) {
        // RY0 on r bit 4 (incoming CZ folded into X0/Y0)
#pragma unroll
        for (int g = 0; g < 16; ++g) {
            const float a_ = v[g], b_ = v[g | 16];
            v[g]      = cw[0] * a_ + X0 * b_;
            v[g | 16] = sw[0] * a_ + Y0 * b_;
        }
        RY_REG_F(3, 16, cw[1], sw[1])   // RY1, fold CZ(0,1)
        RY_REG_F(2, 8,  cw[2], sw[2])   // RY2, fold CZ(1,2)
        RY_REG_F(1, 4,  cw[3], sw[3])   // RY3, fold CZ(2,3)
        RY_REG_F(0, 2,  cw[4], sw[4])   // RY4, fold CZ(3,4)

        // RY5 (lane bit5), fold CZ(4,5) (r bit0 & lane bit5) — DS shuffle
#pragma unroll
        for (int r = 0; r < 32; ++r) {
            const float pa_ = shfl32(v[r]);
            v[r] = (r & 1) ? (C5m  * v[r] + sw[5] * pa_)
                           : (cw[5] * v[r] + SS5  * pa_);
        }
        RY_LANE_G(shfl16, C6m,  S6m)    // RY6,  fold CZ(5,6)  — DS shuffle
        RY_LANE_G(dppx8,  C7m,  S7m)    // RY7,  fold CZ(6,7)  — DPP
        RY_LANE_G(dppx4,  C8m,  S8m)    // RY8,  fold CZ(7,8)  — DPP x2
        RY_LANE_G(dppx2,  C9m,  S9m)    // RY9,  fold CZ(8,9)  — DPP
        RY_LANE_G(dppx1,  C10m, S10m)   // RY10, fold CZ(9,10) — DPP
        // CZ(10,0) -> folded into next layer's RY0; pure sign after last layer.
    };

    layer(-sw[0], cw[0]);               // layer 0: RY0 has no incoming CZ
#pragma unroll 1
    for (int l = 1; l < 6; ++l) layer(X0m, Y0m);

    // ---- measurement: out[w] = sum_i amp_i^2 * (1 - 2*bit_w(i)) ----
    float p[32];
#pragma unroll
    for (int r = 0; r < 32; ++r) p[r] = v[r] * v[r];

    float tot = 0.f;
#pragma unroll
    for (int r = 0; r < 32; ++r) tot += p[r];

    float S4 = 0.f, S3 = 0.f, S2 = 0.f, S1 = 0.f, S0 = 0.f;
#pragma unroll
    for (int r = 0; r < 32; ++r) {
        if (r & 16) S4 += p[r];
        if (r & 8)  S3 += p[r];
        if (r & 4)  S2 += p[r];
        if (r & 2)  S1 += p[r];
        if (r & 1)  S0 += p[r];
    }

    float q[NQ];
    q[0] = tot - 2.f * S4;
    q[1] = tot - 2.f * S3;
    q[2] = tot - 2.f * S2;
    q[3] = tot - 2.f * S1;
    q[4] = tot - 2.f * S0;
    q[5]  = (lane & 32) ? -tot : tot;
    q[6]  = (lane & 16) ? -tot : tot;
    q[7]  = (lane & 8)  ? -tot : tot;
    q[8]  = (lane & 4)  ? -tot : tot;
    q[9]  = (lane & 2)  ? -tot : tot;
    q[10] = (lane & 1)  ? -tot : tot;

#pragma unroll
    for (int wq = 0; wq < NQ; ++wq) {
        float a = q[wq];
        a += __shfl_xor(a, 32);
        a += __shfl_xor(a, 16);
        a += dpp_mov<DPP_XOR8>(a);
        a += dpp_mov<DPP_XOR3>(dpp_mov<DPP_XOR7>(a));
        a += dpp_mov<DPP_XOR2>(a);
        a += dpp_mov<DPP_XOR1>(a);
        q[wq] = a;
    }

    if (lane == 0) {
#pragma unroll
        for (int wq = 0; wq < NQ; ++wq) out[n * 11 + wq] = q[wq];
    }
}

extern "C" void kernel_launch(void* const* d_in, const int* in_sizes, int n_in,
                              void* d_out, int out_size, void* d_ws, size_t ws_size,
                              hipStream_t stream) {
    const float* x = (const float*)d_in[0];   // [8,256,16] f32
    const float* w = (const float*)d_in[1];   // [11] f32
    float* out = (float*)d_out;               // [8,256,11] f32

    qru_kernel<<<512, 256, 0, stream>>>(x, w, out);
}

// Round 6
// 25.654 us; speedup vs baseline: 1.6002x; 1.1002x over previous
//
#include <hip/hip_runtime.h>

#define NQ 11

// One wave per sample; 2048-amplitude real statevector in 16 float2 VGPR
// pairs per lane.  Amplitude index i (wire w <-> bit (10-w) of i):
//   i = (k<<7) | (comp<<6) | lane   with r = (k<<1)|comp
//   wires 0..3  -> k bits 3..0   (packed float2 register butterflies)
//   wire  4     -> comp          (within-float2 butterfly, packed w/ swap)
//   wires 5..10 -> lane bits 5..0 (cross-lane butterflies)
// Every CZ folded into the NEXT RY's coefficients (verified rounds 3/5).
// Cross-lane mechanism: mask 32,16 -> __shfl_xor (DS); mask 8,4,2,1 -> DPP
// (verified round 5).  This round: packed VOP3P math (v_pk_fma_f32).

typedef float f32x2 __attribute__((ext_vector_type(2)));

__device__ __forceinline__ f32x2 b2(float s) { f32x2 r; r.x = s; r.y = s; return r; }
__device__ __forceinline__ f32x2 fma2(f32x2 a, f32x2 b, f32x2 c) {
    return __builtin_elementwise_fma(a, b, c);
}

template <int CTRL>
__device__ __forceinline__ float dpp_mov(float x) {
    const int xi = __builtin_bit_cast(int, x);
    return __builtin_bit_cast(float,
        __builtin_amdgcn_update_dpp(xi, xi, CTRL, 0xf, 0xf, false));
}
#define DPP_XOR1 0xB1   // quad_perm [1,0,3,2]
#define DPP_XOR2 0x4E   // quad_perm [2,3,0,1]
#define DPP_XOR3 0x1B   // quad_perm [3,2,1,0]
#define DPP_XOR7 0x141  // row_half_mirror
#define DPP_XOR8 0x128  // row_ror:8 (xor-8 within 16-lane row)

// Packed butterfly on k-bit KB; preceding CZ sign: -1 iff (k0 & KSB).
#define RY_K_F(KB, KSB, C, S)                                                \
    _Pragma("unroll")                                                        \
    for (int g = 0; g < 8; ++g) {                                            \
        const int k0 = ((g >> (KB)) << ((KB) + 1)) | (g & ((1 << (KB)) - 1));\
        const int k1 = k0 | (1 << (KB));                                     \
        const f32x2 a_ = v2[k0], b_ = v2[k1];                                \
        const f32x2 Cv = b2(C), Sv = b2(S);                                  \
        if (k0 & (KSB)) {  /* sigma1 = -1 */                                 \
            v2[k0] = fma2(Cv, a_, Sv * b_);                                  \
            v2[k1] = fma2(Sv, a_, -(Cv * b_));                               \
        } else {                                                             \
            v2[k0] = fma2(Cv, a_, -(Sv * b_));                               \
            v2[k1] = fma2(Sv, a_, Cv * b_);                                  \
        }                                                                    \
    }

// Packed lane butterfly: partner fetched per 32-bit component by PGETX.
#define RY_LANE2(PGETX, CV, SV)                                              \
    _Pragma("unroll")                                                        \
    for (int k = 0; k < 16; ++k) {                                           \
        f32x2 pa_;                                                           \
        pa_.x = PGETX(v2[k].x);                                              \
        pa_.y = PGETX(v2[k].y);                                              \
        v2[k] = fma2(CV, v2[k], (SV) * pa_);                                 \
    }

__global__ __launch_bounds__(256, 2) void qru_kernel(
    const float* __restrict__ x,   // [2048, 16]
    const float* __restrict__ w,   // [11]
    float* __restrict__ out)       // [2048, 11]
{
    const int lane = threadIdx.x & 63;
    const int n    = blockIdx.x * 4 + (threadIdx.x >> 6);

    // ---- input angles (vectorized) + half-angle sin/cos ----
    const float4 xa = *(const float4*)(x + n * 16);
    const float4 xb = *(const float4*)(x + n * 16 + 4);
    const float4 xc = *(const float4*)(x + n * 16 + 8);
    const float xv[NQ] = {xa.x, xa.y, xa.z, xa.w, xb.x, xb.y, xb.z, xb.w,
                          xc.x, xc.y, xc.z};
    float ci[NQ], si[NQ];
#pragma unroll
    for (int q = 0; q < NQ; ++q) {
        const float h = xv[q] * 0.5f;
        si[q] = __sinf(h); ci[q] = __cosf(h);
    }
    float cw[NQ], sw[NQ];
#pragma unroll
    for (int q = 0; q < NQ; ++q) {
        const float h = w[q] * 0.5f;
        sw[q] = __sinf(h); cw[q] = __cosf(h);
    }

    // ---- initial product state ----
    const float laneF =
        ((lane & 32) ? si[5]  : ci[5])  *
        ((lane & 16) ? si[6]  : ci[6])  *
        ((lane & 8)  ? si[7]  : ci[7])  *
        ((lane & 4)  ? si[8]  : ci[8])  *
        ((lane & 2)  ? si[9]  : ci[9])  *
        ((lane & 1)  ? si[10] : ci[10]);

    f32x2 v2[16];
#pragma unroll
    for (int k = 0; k < 16; ++k) {
        const float base = laneF * ((k & 8) ? si[0] : ci[0])
                                 * ((k & 4) ? si[1] : ci[1])
                                 * ((k & 2) ? si[2] : ci[2])
                                 * ((k & 1) ? si[3] : ci[3]);
        v2[k].x = base * ci[4];
        v2[k].y = base * si[4];
    }

    // ---- folded per-lane coefficient constants (verified rounds 3/5) ----
    // RY0 (k bit3), incoming CZ(10,0): sigma1 = -1 iff lane bit0
    const float X0m = (lane & 1) ?  sw[0] : -sw[0];
    const float Y0m = (lane & 1) ? -cw[0] :  cw[0];
    // RY5 (lane bit5), incoming CZ(4,5) (comp & lane bit5), per-component:
    const float SS5 = (lane & 32) ?  sw[5] : -sw[5];  // comp 0 cross
    const float C5m = (lane & 32) ? -cw[5] :  cw[5];  // comp 1 own
    f32x2 Cv5; Cv5.x = cw[5]; Cv5.y = C5m;
    f32x2 Sv5; Sv5.x = SS5;   Sv5.y = sw[5];
    // lane-lane folds: own = (both bits)? -C : C ; cross = (either)? +S : -S
    const f32x2 C6v  = b2(((lane & 48) == 48) ? -cw[6]  : cw[6]);
    const f32x2 S6v  = b2((lane & 48) ? sw[6]  : -sw[6]);
    const f32x2 C7v  = b2(((lane & 24) == 24) ? -cw[7]  : cw[7]);
    const f32x2 S7v  = b2((lane & 24) ? sw[7]  : -sw[7]);
    const f32x2 C8v  = b2(((lane & 12) == 12) ? -cw[8]  : cw[8]);
    const f32x2 S8v  = b2((lane & 12) ? sw[8]  : -sw[8]);
    const f32x2 C9v  = b2(((lane & 6)  == 6)  ? -cw[9]  : cw[9]);
    const f32x2 S9v  = b2((lane & 6)  ? sw[9]  : -sw[9]);
    const f32x2 C10v = b2(((lane & 3)  == 3)  ? -cw[10] : cw[10]);
    const f32x2 S10v = b2((lane & 3)  ? sw[10] : -sw[10]);

    // RY4 (comp butterfly), incoming CZ(3,4): sigma1 = -1 iff k odd.
    f32x2 C4p; C4p.x = cw[4]; C4p.y =  cw[4];
    f32x2 S4p; S4p.x = -sw[4]; S4p.y = sw[4];
    f32x2 C4m; C4m.x = cw[4]; C4m.y = -cw[4];
    f32x2 S4m; S4m.x = sw[4]; S4m.y =  sw[4];

    auto shfl32 = [](float t) { return __shfl_xor(t, 32); };
    auto shfl16 = [](float t) { return __shfl_xor(t, 16); };
    auto dppx8  = [](float t) { return dpp_mov<DPP_XOR8>(t); };
    auto dppx4  = [](float t) { return dpp_mov<DPP_XOR3>(dpp_mov<DPP_XOR7>(t)); };
    auto dppx2  = [](float t) { return dpp_mov<DPP_XOR2>(t); };
    auto dppx1  = [](float t) { return dpp_mov<DPP_XOR1>(t); };

    auto layer = [&](float X0, float Y0) {
        // RY0 on k bit 3 (incoming CZ folded into X0/Y0)
        {
            const f32x2 c0 = b2(cw[0]), s0 = b2(sw[0]);
            const f32x2 x0 = b2(X0),    y0 = b2(Y0);
#pragma unroll
            for (int k = 0; k < 8; ++k) {
                const f32x2 a_ = v2[k], b_ = v2[k | 8];
                v2[k]     = fma2(c0, a_, x0 * b_);
                v2[k | 8] = fma2(s0, a_, y0 * b_);
            }
        }
        RY_K_F(2, 8, cw[1], sw[1])      // RY1 (k bit2), fold CZ(0,1) (k bit3)
        RY_K_F(1, 4, cw[2], sw[2])      // RY2 (k bit1), fold CZ(1,2) (k bit2)
        RY_K_F(0, 2, cw[3], sw[3])      // RY3 (k bit0), fold CZ(2,3) (k bit1)

        // RY4 (component), fold CZ(3,4) (k bit0)
#pragma unroll
        for (int k = 0; k < 16; ++k) {
            const f32x2 s_ = __builtin_shufflevector(v2[k], v2[k], 1, 0);
            v2[k] = (k & 1) ? fma2(C4m, v2[k], S4m * s_)
                            : fma2(C4p, v2[k], S4p * s_);
        }

        RY_LANE2(shfl32, Cv5, Sv5)      // RY5,  fold CZ(4,5)  — DS
        RY_LANE2(shfl16, C6v, S6v)      // RY6,  fold CZ(5,6)  — DS
        RY_LANE2(dppx8,  C7v, S7v)      // RY7,  fold CZ(6,7)  — DPP
        RY_LANE2(dppx4,  C8v, S8v)      // RY8,  fold CZ(7,8)  — DPP x2
        RY_LANE2(dppx2,  C9v, S9v)      // RY9,  fold CZ(8,9)  — DPP
        RY_LANE2(dppx1,  C10v, S10v)    // RY10, fold CZ(9,10) — DPP
        // CZ(10,0) -> folded into next layer's RY0; pure sign after last.
    };

    layer(-sw[0], cw[0]);               // layer 0: RY0 has no incoming CZ
#pragma unroll 1
    for (int l = 1; l < 6; ++l) layer(X0m, Y0m);

    // ---- measurement: out[w] = sum_i amp_i^2 * (1 - 2*bit_w(i)) ----
    f32x2 T = b2(0.f), A3 = b2(0.f), A2 = b2(0.f), A1 = b2(0.f), A0 = b2(0.f);
#pragma unroll
    for (int k = 0; k < 16; ++k) {
        const f32x2 p = v2[k] * v2[k];
        T = T + p;
        if (k & 8) A3 = A3 + p;
        if (k & 4) A2 = A2 + p;
        if (k & 2) A1 = A1 + p;
        if (k & 1) A0 = A0 + p;
    }
    const float tot = T.x + T.y;

    float q[NQ];
    q[0] = tot - 2.f * (A3.x + A3.y);   // wire 0 (k bit3)
    q[1] = tot - 2.f * (A2.x + A2.y);   // wire 1 (k bit2)
    q[2] = tot - 2.f * (A1.x + A1.y);   // wire 2 (k bit1)
    q[3] = tot - 2.f * (A0.x + A0.y);   // wire 3 (k bit0)
    q[4] = tot - 2.f * T.y;             // wire 4 (comp)
    q[5]  = (lane & 32) ? -tot : tot;   // wires 5..10 (lane bits 5..0)
    q[6]  = (lane & 16) ? -tot : tot;
    q[7]  = (lane & 8)  ? -tot : tot;
    q[8]  = (lane & 4)  ? -tot : tot;
    q[9]  = (lane & 2)  ? -tot : tot;
    q[10] = (lane & 1)  ? -tot : tot;

#pragma unroll
    for (int wq = 0; wq < NQ; ++wq) {
        float a = q[wq];
        a += __shfl_xor(a, 32);
        a += __shfl_xor(a, 16);
        a += dpp_mov<DPP_XOR8>(a);
        a += dpp_mov<DPP_XOR3>(dpp_mov<DPP_XOR7>(a));
        a += dpp_mov<DPP_XOR2>(a);
        a += dpp_mov<DPP_XOR1>(a);
        q[wq] = a;
    }

    if (lane == 0) {
#pragma unroll
        for (int wq = 0; wq < NQ; ++wq) out[n * 11 + wq] = q[wq];
    }
}

extern "C" void kernel_launch(void* const* d_in, const int* in_sizes, int n_in,
                              void* d_out, int out_size, void* d_ws, size_t ws_size,
                              hipStream_t stream) {
    const float* x = (const float*)d_in[0];   // [8,256,16] f32
    const float* w = (const float*)d_in[1];   // [11] f32
    float* out = (float*)d_out;               // [8,256,11] f32

    qru_kernel<<<512, 256, 0, stream>>>(x, w, out);
}